// Round 5
// baseline (70.651 us; speedup 1.0000x reference)
//
#include <hip/hip_runtime.h>

#define BATCH 256
#define IN1   10240
#define NU    32
#define SPLITS 128
#define STRIPE (IN1 / SPLITS)   // 80
#define SUB   16                // i sub-chunk held in registers
#define NSUB  (STRIPE / SUB)    // 5
#define LOG2E 1.4426950408889634f

// ---------------- Kernel 0: pack transformed params -----------------------
// Ppack layout: [uq][i][uj] float4 {A, C, W, W*erev}, uq = u>>3, uj = u&7.
// A = iw*ssig*log2e, C = (smu - ib)*ssig*log2e.
__global__ __launch_bounds__(256) void ltc_pack(
    const float* __restrict__ iw, const float* __restrict__ ibias,
    const float* __restrict__ smu, const float* __restrict__ ssig,
    const float* __restrict__ sW, const float* __restrict__ serev,
    float4* __restrict__ Ppack)
{
    const int idx = blockIdx.x * 256 + threadIdx.x;   // 0..IN1*NU-1
    const int i = idx >> 5;
    const int u = idx & 31;
    const float sg = ssig[idx] * LOG2E;
    const float A  = sg * iw[i];
    const float C  = (smu[idx] - ibias[i]) * sg;
    const float w  = sW[idx];
    const int uq = u >> 3, uj = u & 7;
    Ppack[((size_t)uq * IN1 + i) * 8 + uj] =
        make_float4(A, C, w, w * serev[idx]);
}

// ---------------- Kernel 1: sensory partial sums --------------------------
// grid = (4 u-quarters, SPLITS stripes); block = 256 threads = 256 batches
// (lane = batch). Params are wave-uniform -> scalar-cache loads; x rows are
// per-lane contiguous -> dwordx4 into registers. No LDS at all.
__global__ __launch_bounds__(256) void ltc_sensory_partial(
    const float* __restrict__ x,
    const float4* __restrict__ Ppack,
    float2* __restrict__ part)
{
    const int b  = threadIdx.x;          // batch
    const int uq = blockIdx.x;           // 0..3 (fast dim: x shared in L2)
    const int s  = blockIdx.y;           // 0..SPLITS-1
    const int i0 = s * STRIPE;

    float accn[8], accd[8];
#pragma unroll
    for (int k = 0; k < 8; ++k) { accn[k] = 0.f; accd[k] = 0.f; }

    const float*  xrow  = x + (size_t)b * IN1 + i0;
    const float4* pbase = Ppack + ((size_t)uq * IN1 + i0) * 8;

    for (int sc = 0; sc < NSUB; ++sc) {
        union { float4 v4[SUB / 4]; float f[SUB]; } xu;
#pragma unroll
        for (int q = 0; q < SUB / 4; ++q)
            xu.v4[q] = *(const float4*)(xrow + sc * SUB + q * 4);

#pragma unroll
        for (int di = 0; di < SUB; ++di) {
            const float xv = xu.f[di];
            const float4* pp = pbase + (size_t)(sc * SUB + di) * 8;
#pragma unroll
            for (int uj = 0; uj < 8; ++uj) {
                const float4 f = pp[uj];               // wave-uniform -> SGPR
                const float t = f.y - xv * f.x;        // C - x*A
                const float e = __builtin_amdgcn_exp2f(t);
                const float r = __builtin_amdgcn_rcpf(1.0f + e);
                accd[uj] = fmaf(f.z, r, accd[uj]);
                accn[uj] = fmaf(f.w, r, accn[uj]);
            }
        }
    }

    float2* po = part + ((size_t)s * BATCH + b) * NU + uq * 8;
#pragma unroll
    for (int uj = 0; uj < 8; ++uj)
        po[uj] = make_float2(accn[uj], accd[uj]);
}

// ---------------- Kernel 2: reduce split partials -------------------------
__global__ __launch_bounds__(256) void ltc_reduce(
    const float2* __restrict__ part, int nsplit, float2* __restrict__ S)
{
    const int tid = threadIdx.x;
    const int b   = blockIdx.x;
    const int u   = tid & 31;
    const int sl  = tid >> 5;

    __shared__ float sred[8][NU][2];

    float sn = 0.f, sd = 0.f;
#pragma unroll 8
    for (int s = sl; s < nsplit; s += 8) {
        const float2 p = part[((size_t)s * BATCH + b) * NU + u];
        sn += p.x;
        sd += p.y;
    }
    sred[sl][u][0] = sn;
    sred[sl][u][1] = sd;
    __syncthreads();

    if (tid >= 32) return;
    float Sn = 0.f, Sd = 0.f;
#pragma unroll
    for (int s2 = 0; s2 < 8; ++s2) {
        Sn += sred[s2][u][0];
        Sd += sred[s2][u][1];
    }
    S[(size_t)b * NU + u] = make_float2(Sn, Sd);
}

// ---------------- Kernel 3: unfolds + cell B + output ---------------------
__global__ __launch_bounds__(256) void ltc_unfold(
    const float2* __restrict__ S,
    const float* __restrict__ amu, const float* __restrict__ asig,
    const float* __restrict__ aW,  const float* __restrict__ aerev,
    const float* __restrict__ agleak, const float* __restrict__ avleak,
    const float* __restrict__ acm,
    const float* __restrict__ b_iw, const float* __restrict__ b_ib,
    const float* __restrict__ b_smu, const float* __restrict__ b_ssig,
    const float* __restrict__ b_sW,  const float* __restrict__ b_serev,
    const float* __restrict__ b_mu,  const float* __restrict__ b_sig,
    const float* __restrict__ b_W,   const float* __restrict__ b_erev,
    const float* __restrict__ b_gleak, const float* __restrict__ b_vleak,
    const float* __restrict__ b_cm,
    float* __restrict__ out)
{
    const int tid = threadIdx.x;
    const int u   = tid & 31;
    const int bl  = tid >> 5;
    const int b   = blockIdx.x * 8 + bl;

    __shared__ float pAp[NU*NU], pCp[NU*NU];
    __shared__ float pW[NU*NU],  pWE[NU*NU];

    for (int p = tid; p < NU * NU; p += 256) {
        const float sg = asig[p] * LOG2E;
        pAp[p] = sg;
        pCp[p] = amu[p] * sg;
        const float w = aW[p];
        pW[p]  = w;
        pWE[p] = w * aerev[p];
    }
    __syncthreads();

    const float2 Sv = S[(size_t)b * NU + u];
    const float Sn = Sv.x, Sd = Sv.y;

    const float cmt = acm[u] * 6.0f;
    const float gl  = agleak[u];
    const float gv  = gl * avleak[u];

    float v = 0.f;
    for (int k = 0; k < 6; ++k) {
        float rn = 0.f, rd = 0.f;
#pragma unroll
        for (int j = 0; j < NU; ++j) {
            const float vj = __shfl(v, j, 32);
            const int pi = j * NU + u;
            const float e = __builtin_amdgcn_exp2f(pCp[pi] - vj * pAp[pi]);
            const float r = __builtin_amdgcn_rcpf(1.0f + e);
            rn = fmaf(pWE[pi], r, rn);
            rd = fmaf(pW[pi],  r, rd);
        }
        const float num = cmt * v + gv + rn + Sn;
        const float den = cmt + gl + rd + Sd;
        v = num / den;
    }

    const float x2  = v * b_iw[u] + b_ib[u];
    const float e2  = __builtin_amdgcn_exp2f((b_smu[u] - x2) * b_ssig[u] * LOG2E);
    const float s2v = b_sW[u] * __builtin_amdgcn_rcpf(1.0f + e2);
    float wn = s2v * b_serev[u];
    float wd = s2v;
#pragma unroll
    for (int m = 16; m >= 1; m >>= 1) {
        wn += __shfl_xor(wn, m, 32);
        wd += __shfl_xor(wd, m, 32);
    }

    const float bcmt = b_cm[0] * 6.0f;
    const float bgl  = b_gleak[0];
    const float bgv  = bgl * b_vleak[0];
    const float bmu  = b_mu[0], bsig = b_sig[0], bW = b_W[0], berev = b_erev[0];
    float v2 = 0.f;
#pragma unroll
    for (int k = 0; k < 6; ++k) {
        const float ee = __builtin_amdgcn_exp2f((bmu - v2) * bsig * LOG2E);
        const float ws = bW * __builtin_amdgcn_rcpf(1.0f + ee);
        const float num = bcmt * v2 + bgv + ws * berev + wn;
        const float den = bcmt + bgl + ws + wd;
        v2 = num / den;
    }

    if (u == 0)
        out[b] = 1.0f / (1.0f + __builtin_amdgcn_exp2f(-v2 * LOG2E));
}

extern "C" void kernel_launch(void* const* d_in, const int* in_sizes, int n_in,
                              void* d_out, int out_size, void* d_ws, size_t ws_size,
                              hipStream_t stream) {
    const float* x       = (const float*)d_in[0];
    const float* a_iw    = (const float*)d_in[1];
    const float* a_ib    = (const float*)d_in[2];
    const float* a_smu   = (const float*)d_in[3];
    const float* a_ssig  = (const float*)d_in[4];
    const float* a_sW    = (const float*)d_in[5];
    const float* a_serev = (const float*)d_in[6];
    const float* a_mu    = (const float*)d_in[7];
    const float* a_sig   = (const float*)d_in[8];
    const float* a_W     = (const float*)d_in[9];
    const float* a_erev  = (const float*)d_in[10];
    const float* a_gleak = (const float*)d_in[11];
    const float* a_vleak = (const float*)d_in[12];
    const float* a_cm    = (const float*)d_in[13];
    const float* b_iw    = (const float*)d_in[14];
    const float* b_ib    = (const float*)d_in[15];
    const float* b_smu   = (const float*)d_in[16];
    const float* b_ssig  = (const float*)d_in[17];
    const float* b_sW    = (const float*)d_in[18];
    const float* b_serev = (const float*)d_in[19];
    const float* b_mu    = (const float*)d_in[20];
    const float* b_sig   = (const float*)d_in[21];
    const float* b_W     = (const float*)d_in[22];
    const float* b_erev  = (const float*)d_in[23];
    const float* b_gleak = (const float*)d_in[24];
    const float* b_vleak = (const float*)d_in[25];
    const float* b_cm    = (const float*)d_in[26];
    float* out = (float*)d_out;

    float4* Ppack = (float4*)d_ws;                               // 5.24 MB
    float2* part  = (float2*)(Ppack + (size_t)IN1 * NU);         // 8.39 MB
    float2* Sarr  = part + (size_t)SPLITS * BATCH * NU;          // 16 KB

    ltc_pack<<<(IN1 * NU) / 256, 256, 0, stream>>>(
        a_iw, a_ib, a_smu, a_ssig, a_sW, a_serev, Ppack);

    dim3 g1(4, SPLITS);
    ltc_sensory_partial<<<g1, 256, 0, stream>>>(x, Ppack, part);

    ltc_reduce<<<BATCH, 256, 0, stream>>>(part, SPLITS, Sarr);

    ltc_unfold<<<BATCH / 8, 256, 0, stream>>>(
        Sarr,
        a_mu, a_sig, a_W, a_erev, a_gleak, a_vleak, a_cm,
        b_iw, b_ib, b_smu, b_ssig, b_sW, b_serev,
        b_mu, b_sig, b_W, b_erev, b_gleak, b_vleak, b_cm,
        out);
}

// Round 6
// 59.537 us; speedup vs baseline: 1.1867x; 1.1867x over previous
//
#include <hip/hip_runtime.h>

#define BATCH 256
#define IN1   10240
#define NU    32
#define SPLITS 256
#define STRIPE (IN1 / SPLITS)   // 40
#define SUB   8                 // x floats held in registers per step
#define NSUB  (STRIPE / SUB)    // 5
#define LOG2E 1.4426950408889634f

// ---------------- Kernel 0: pack transformed params -----------------------
// Ppack layout: [uq][i][uj] float4 {A, C, W, W*erev}, uq = u>>3, uj = u&7.
__global__ __launch_bounds__(256) void ltc_pack(
    const float* __restrict__ iw, const float* __restrict__ ibias,
    const float* __restrict__ smu, const float* __restrict__ ssig,
    const float* __restrict__ sW, const float* __restrict__ serev,
    float4* __restrict__ Ppack)
{
    const int idx = blockIdx.x * 256 + threadIdx.x;   // 0..IN1*NU-1
    const int i = idx >> 5;
    const int u = idx & 31;
    const float sg = ssig[idx] * LOG2E;
    const float A  = sg * iw[i];
    const float C  = (smu[idx] - ibias[i]) * sg;
    const float w  = sW[idx];
    const int uq = u >> 3, uj = u & 7;
    Ppack[((size_t)uq * IN1 + i) * 8 + uj] =
        make_float4(A, C, w, w * serev[idx]);
}

// ---------------- Kernel 1: sensory partial sums --------------------------
// grid = (4 u-quarters, SPLITS stripes); block = 256 threads = 256 batches
// (lane = batch). Params wave-uniform (scalar loads), manually double-
// buffered one i ahead so the s_load batch flies under current-i VALU.
__global__ __launch_bounds__(256) void ltc_sensory_partial(
    const float* __restrict__ x,
    const float4* __restrict__ Ppack,
    float2* __restrict__ part)
{
    const int b  = threadIdx.x;          // batch
    const int uq = blockIdx.x;           // 0..3
    const int s  = blockIdx.y;           // 0..SPLITS-1
    const int i0 = s * STRIPE;

    float accn[8], accd[8];
#pragma unroll
    for (int k = 0; k < 8; ++k) { accn[k] = 0.f; accd[k] = 0.f; }

    const float*  xrow  = x + (size_t)b * IN1 + i0;
    const float4* pbase = Ppack + ((size_t)uq * IN1 + i0) * 8;

    float4 fc[8];
#pragma unroll
    for (int uj = 0; uj < 8; ++uj) fc[uj] = pbase[uj];

    for (int sc = 0; sc < NSUB; ++sc) {
        union { float4 v4[SUB / 4]; float f[SUB]; } xu;
#pragma unroll
        for (int q = 0; q < SUB / 4; ++q)
            xu.v4[q] = *(const float4*)(xrow + sc * SUB + q * 4);

#pragma unroll
        for (int di = 0; di < SUB; ++di) {
            const int cur = sc * SUB + di;
            // prefetch next i's params (slack-padded past Ppack end)
            float4 fn[8];
            const float4* pn = pbase + (size_t)(cur + 1) * 8;
#pragma unroll
            for (int uj = 0; uj < 8; ++uj) fn[uj] = pn[uj];

            const float xv = xu.f[di];
#pragma unroll
            for (int uj = 0; uj < 8; ++uj) {
                const float4 f = fc[uj];
                const float e = __builtin_amdgcn_exp2f(f.y - xv * f.x);
                const float r = __builtin_amdgcn_rcpf(1.0f + e);
                accd[uj] = fmaf(f.z, r, accd[uj]);
                accn[uj] = fmaf(f.w, r, accn[uj]);
            }
#pragma unroll
            for (int uj = 0; uj < 8; ++uj) fc[uj] = fn[uj];
        }
    }

    float2* po = part + ((size_t)s * BATCH + b) * NU + uq * 8;
#pragma unroll
    for (int uj = 0; uj < 8; ++uj)
        po[uj] = make_float2(accn[uj], accd[uj]);
}

// ---------------- Kernel 2: reduce split partials -------------------------
__global__ __launch_bounds__(256) void ltc_reduce(
    const float2* __restrict__ part, int nsplit, float2* __restrict__ S)
{
    const int tid = threadIdx.x;
    const int b   = blockIdx.x;
    const int u   = tid & 31;
    const int sl  = tid >> 5;

    __shared__ float sred[8][NU][2];

    float sn = 0.f, sd = 0.f;
#pragma unroll 8
    for (int s = sl; s < nsplit; s += 8) {
        const float2 p = part[((size_t)s * BATCH + b) * NU + u];
        sn += p.x;
        sd += p.y;
    }
    sred[sl][u][0] = sn;
    sred[sl][u][1] = sd;
    __syncthreads();

    if (tid >= 32) return;
    float Sn = 0.f, Sd = 0.f;
#pragma unroll
    for (int s2 = 0; s2 < 8; ++s2) {
        Sn += sred[s2][u][0];
        Sd += sred[s2][u][1];
    }
    S[(size_t)b * NU + u] = make_float2(Sn, Sd);
}

// ---------------- Kernel 3: unfolds + cell B + output ---------------------
__global__ __launch_bounds__(256) void ltc_unfold(
    const float2* __restrict__ S,
    const float* __restrict__ amu, const float* __restrict__ asig,
    const float* __restrict__ aW,  const float* __restrict__ aerev,
    const float* __restrict__ agleak, const float* __restrict__ avleak,
    const float* __restrict__ acm,
    const float* __restrict__ b_iw, const float* __restrict__ b_ib,
    const float* __restrict__ b_smu, const float* __restrict__ b_ssig,
    const float* __restrict__ b_sW,  const float* __restrict__ b_serev,
    const float* __restrict__ b_mu,  const float* __restrict__ b_sig,
    const float* __restrict__ b_W,   const float* __restrict__ b_erev,
    const float* __restrict__ b_gleak, const float* __restrict__ b_vleak,
    const float* __restrict__ b_cm,
    float* __restrict__ out)
{
    const int tid = threadIdx.x;
    const int u   = tid & 31;
    const int bl  = tid >> 5;
    const int b   = blockIdx.x * 8 + bl;

    __shared__ float pAp[NU*NU], pCp[NU*NU];
    __shared__ float pW[NU*NU],  pWE[NU*NU];

    for (int p = tid; p < NU * NU; p += 256) {
        const float sg = asig[p] * LOG2E;
        pAp[p] = sg;
        pCp[p] = amu[p] * sg;
        const float w = aW[p];
        pW[p]  = w;
        pWE[p] = w * aerev[p];
    }
    __syncthreads();

    const float2 Sv = S[(size_t)b * NU + u];
    const float Sn = Sv.x, Sd = Sv.y;

    const float cmt = acm[u] * 6.0f;
    const float gl  = agleak[u];
    const float gv  = gl * avleak[u];

    float v = 0.f;
    for (int k = 0; k < 6; ++k) {
        float rn = 0.f, rd = 0.f;
#pragma unroll
        for (int j = 0; j < NU; ++j) {
            const float vj = __shfl(v, j, 32);
            const int pi = j * NU + u;
            const float e = __builtin_amdgcn_exp2f(pCp[pi] - vj * pAp[pi]);
            const float r = __builtin_amdgcn_rcpf(1.0f + e);
            rn = fmaf(pWE[pi], r, rn);
            rd = fmaf(pW[pi],  r, rd);
        }
        const float num = cmt * v + gv + rn + Sn;
        const float den = cmt + gl + rd + Sd;
        v = num / den;
    }

    const float x2  = v * b_iw[u] + b_ib[u];
    const float e2  = __builtin_amdgcn_exp2f((b_smu[u] - x2) * b_ssig[u] * LOG2E);
    const float s2v = b_sW[u] * __builtin_amdgcn_rcpf(1.0f + e2);
    float wn = s2v * b_serev[u];
    float wd = s2v;
#pragma unroll
    for (int m = 16; m >= 1; m >>= 1) {
        wn += __shfl_xor(wn, m, 32);
        wd += __shfl_xor(wd, m, 32);
    }

    const float bcmt = b_cm[0] * 6.0f;
    const float bgl  = b_gleak[0];
    const float bgv  = bgl * b_vleak[0];
    const float bmu  = b_mu[0], bsig = b_sig[0], bW = b_W[0], berev = b_erev[0];
    float v2 = 0.f;
#pragma unroll
    for (int k = 0; k < 6; ++k) {
        const float ee = __builtin_amdgcn_exp2f((bmu - v2) * bsig * LOG2E);
        const float ws = bW * __builtin_amdgcn_rcpf(1.0f + ee);
        const float num = bcmt * v2 + bgv + ws * berev + wn;
        const float den = bcmt + bgl + ws + wd;
        v2 = num / den;
    }

    if (u == 0)
        out[b] = 1.0f / (1.0f + __builtin_amdgcn_exp2f(-v2 * LOG2E));
}

extern "C" void kernel_launch(void* const* d_in, const int* in_sizes, int n_in,
                              void* d_out, int out_size, void* d_ws, size_t ws_size,
                              hipStream_t stream) {
    const float* x       = (const float*)d_in[0];
    const float* a_iw    = (const float*)d_in[1];
    const float* a_ib    = (const float*)d_in[2];
    const float* a_smu   = (const float*)d_in[3];
    const float* a_ssig  = (const float*)d_in[4];
    const float* a_sW    = (const float*)d_in[5];
    const float* a_serev = (const float*)d_in[6];
    const float* a_mu    = (const float*)d_in[7];
    const float* a_sig   = (const float*)d_in[8];
    const float* a_W     = (const float*)d_in[9];
    const float* a_erev  = (const float*)d_in[10];
    const float* a_gleak = (const float*)d_in[11];
    const float* a_vleak = (const float*)d_in[12];
    const float* a_cm    = (const float*)d_in[13];
    const float* b_iw    = (const float*)d_in[14];
    const float* b_ib    = (const float*)d_in[15];
    const float* b_smu   = (const float*)d_in[16];
    const float* b_ssig  = (const float*)d_in[17];
    const float* b_sW    = (const float*)d_in[18];
    const float* b_serev = (const float*)d_in[19];
    const float* b_mu    = (const float*)d_in[20];
    const float* b_sig   = (const float*)d_in[21];
    const float* b_W     = (const float*)d_in[22];
    const float* b_erev  = (const float*)d_in[23];
    const float* b_gleak = (const float*)d_in[24];
    const float* b_vleak = (const float*)d_in[25];
    const float* b_cm    = (const float*)d_in[26];
    float* out = (float*)d_out;

    float4* Ppack = (float4*)d_ws;                               // 5.24 MB
    // +8 float4 slack: last prefetch reads one i past the end
    float2* part  = (float2*)(Ppack + (size_t)IN1 * NU + 8);     // 16.8 MB
    float2* Sarr  = part + (size_t)SPLITS * BATCH * NU;          // 16 KB

    ltc_pack<<<(IN1 * NU) / 256, 256, 0, stream>>>(
        a_iw, a_ib, a_smu, a_ssig, a_sW, a_serev, Ppack);

    dim3 g1(4, SPLITS);
    ltc_sensory_partial<<<g1, 256, 0, stream>>>(x, Ppack, part);

    ltc_reduce<<<BATCH, 256, 0, stream>>>(part, SPLITS, Sarr);

    ltc_unfold<<<BATCH / 8, 256, 0, stream>>>(
        Sarr,
        a_mu, a_sig, a_W, a_erev, a_gleak, a_vleak, a_cm,
        b_iw, b_ib, b_smu, b_ssig, b_sW, b_serev,
        b_mu, b_sig, b_W, b_erev, b_gleak, b_vleak, b_cm,
        out);
}